// Round 4
// baseline (1126.069 us; speedup 1.0000x reference)
//
#include <hip/hip_runtime.h>
#include <stdint.h>

#define TT 16

typedef float v2f __attribute__((ext_vector_type(2)));

// Locked reference semantics (R7 variant A, verified):
//   cur1 = fmaf(x2,w2, fmaf(x1,w1, x0*w0)) + b1          (f32, fma ascending)
//   mem  = fmaf(0.9f, mem, cur) - reset                  (fused recurrence)
//   dots = single-acc ascending-h masked adds, bias added after dot
// Exact rewrites: masked add == fma(m,w,acc), m in {0.0f,1.0f}; pk-fma is
// componentwise IEEE; spike bits in VGPRs + v_readlane.
// R11: t-packed accumulators, SALU mask pairs (u64 of {0x3F800000|0}),
// weight broadcast via VOP3P op_sel. Bit-exact.
// R12 (this round): TWO SAMPLES PER WAVE. R1/R3 both pinned at ~1.6M cycles
// = the per-CU TA/L1 line budget (B: 256 dwordx4 = 16 lines each; C: 512
// gathers = 16 lines each; x128 waves/CU ~= 1.54M line-cycles at 1 line/cyc).
// All weight traffic is sample-independent -> one load feeds 2 samples.
// Line traffic/CU halves; VALU (invariant ~0.96M cyc/SIMD) becomes the
// limiter. launch_bounds (256,2): accumulators double (aB = 128 VGPR live);
// cap 256 VGPR so NO SPILLS (R2 lesson: spills, not occupancy, are the
// catastrophe mode).
// R10/R2 LESSON (do not repeat): removing `if(p)` lets the scheduler hoist
// loads across iterations -> VGPR blowup -> spill churn -> 2.3x slower.
// The `if(p0|p1)` is a live-range fence; keep loads inside it.
// READLANE LEGALITY (R8 bug): llvm.amdgcn.readlane from an inactive lane is
// undefined. All readlanes (and their defs) sit in uniform control flow.
// Phase C runs on all 64 lanes; lanes 50..63 compute a clamped duplicate
// head; only the final store is divergent.
__device__ __forceinline__ float lstep(float mem, float cur) {
    const float reset = (mem > 1.0f) ? 1.0f : 0.0f;
    return __builtin_fmaf(0.9f, mem, cur) - reset;
}

// {m_t, m_t+1} as two u32 float-bit-patterns in one u64 (lo = t, hi = t+1).
// p is wave-uniform (readlane result) -> pure SALU (s_bfe + s_mul per half).
__device__ __forceinline__ uint64_t mask_pair(uint32_t p, int tp) {
    const uint32_t lo = ((p >> (2 * tp)) & 1u) * 0x3F800000u;
    const uint32_t hi = ((p >> (2 * tp + 1)) & 1u) * 0x3F800000u;
    return ((uint64_t)hi << 32) | (uint64_t)lo;
}

// acc.{lo,hi} += m.{lo,hi} * broadcast(w.lo)   [src1 lo-half to both lanes]
#define PKFMA_BLO(acc, mp, w)                                              \
    asm("v_pk_fma_f32 %0, %1, %2, %0 op_sel:[0,0,0] op_sel_hi:[1,0,1]"     \
        : "+v"(acc) : "s"(mp), "v"(w))
// acc.{lo,hi} += m.{lo,hi} * broadcast(w.hi)   [src1 hi-half to both lanes]
#define PKFMA_BHI(acc, mp, w)                                              \
    asm("v_pk_fma_f32 %0, %1, %2, %0 op_sel:[0,1,0] op_sel_hi:[1,1,1]"     \
        : "+v"(acc) : "s"(mp), "v"(w))

__global__ __launch_bounds__(256, 2) void snn_fast(
    const float* __restrict__ x,     // [B,3]
    const float* __restrict__ W1,    // [3,256]
    const float* __restrict__ b1,    // [256]
    const float* __restrict__ W2,    // [256,256]
    const float* __restrict__ b2,    // [256]
    const float* __restrict__ Wout,  // [25,256,4]
    const float* __restrict__ bout,  // [25,4]
    float* __restrict__ out)         // [B,25,4]
{
#pragma clang fp contract(off)
    const int tid = threadIdx.x;
    const int l   = tid & 63;                 // lane; owns hidden units 4l..4l+3
    const int b0  = blockIdx.x * 8 + (tid >> 6);   // sample 0
    const int b1s = b0 + 4;                         // sample 1

    // ---------------- Phase A: layer 1, both samples ----------------
    const float4 w1r0 = ((const float4*)W1)[l];
    const float4 w1r1 = ((const float4*)W1)[64 + l];
    const float4 w1r2 = ((const float4*)W1)[128 + l];
    const float4 b1v  = ((const float4*)b1)[l];

    const float wa0[4] = {w1r0.x, w1r0.y, w1r0.z, w1r0.w};
    const float wa1[4] = {w1r1.x, w1r1.y, w1r1.z, w1r1.w};
    const float wa2[4] = {w1r2.x, w1r2.y, w1r2.z, w1r2.w};
    const float bb1[4] = {b1v.x, b1v.y, b1v.z, b1v.w};

    const float xs[2][3] = {
        {x[b0 * 3 + 0], x[b0 * 3 + 1], x[b0 * 3 + 2]},
        {x[b1s * 3 + 0], x[b1s * 3 + 1], x[b1s * 3 + 2]}};

    uint32_t bits1[2][4];   // [sample][i] spike bits for h = 4l+i, in VGPRs
#pragma unroll
    for (int s = 0; s < 2; ++s) {
#pragma unroll
        for (int i = 0; i < 4; ++i) {
            const float cur = fmaf(xs[s][2], wa2[i],
                             fmaf(xs[s][1], wa1[i], xs[s][0] * wa0[i])) + bb1[i];
            float mem = 0.f; uint32_t p = 0;
#pragma unroll
            for (int t = 0; t < TT; ++t) {
                mem = lstep(mem, cur);
                if (mem > 1.0f) p |= (1u << t);
            }
            bits1[s][i] = p;
        }
    }

    // ------- Phase B: layer 2 — t-packed accs x2 samples, SALU masks -------
    // aB[s][jj][tp] holds {dot_j(2tp), dot_j(2tp+1)} for j = 4l+jj, sample s.
    v2f aB[2][4][8];
#pragma unroll
    for (int s = 0; s < 2; ++s)
#pragma unroll
        for (int jj = 0; jj < 4; ++jj)
#pragma unroll
            for (int tp = 0; tp < 8; ++tp) aB[s][jj][tp] = (v2f)0.f;

    const float4* W2v = (const float4*)W2;
    for (int h4 = 0; h4 < 64; ++h4) {
#pragma unroll
        for (int c = 0; c < 4; ++c) {
            const uint32_t p0 =
                (uint32_t)__builtin_amdgcn_readlane((int)bits1[0][c], h4);
            const uint32_t p1 =
                (uint32_t)__builtin_amdgcn_readlane((int)bits1[1][c], h4);
            if (p0 | p1) {                        // wave-uniform skip + fence
                const float4 w = W2v[(h4 * 4 + c) * 64 + l];
                const v2f w01 = {w.x, w.y};
                const v2f w23 = {w.z, w.w};
#pragma unroll
                for (int tp = 0; tp < 8; ++tp) {
                    const uint64_t mp0 = mask_pair(p0, tp);
                    const uint64_t mp1 = mask_pair(p1, tp);
                    PKFMA_BLO(aB[0][0][tp], mp0, w01);
                    PKFMA_BHI(aB[0][1][tp], mp0, w01);
                    PKFMA_BLO(aB[0][2][tp], mp0, w23);
                    PKFMA_BHI(aB[0][3][tp], mp0, w23);
                    PKFMA_BLO(aB[1][0][tp], mp1, w01);
                    PKFMA_BHI(aB[1][1][tp], mp1, w01);
                    PKFMA_BLO(aB[1][2][tp], mp1, w23);
                    PKFMA_BHI(aB[1][3][tp], mp1, w23);
                }
            }
        }
    }

    const float4 b2v = ((const float4*)b2)[l];
    const float b2a[4] = {b2v.x, b2v.y, b2v.z, b2v.w};
    uint32_t bits2[2][4];
#pragma unroll
    for (int s = 0; s < 2; ++s) {
#pragma unroll
        for (int i = 0; i < 4; ++i) {
            float mem = 0.f; uint32_t p = 0;
#pragma unroll
            for (int t = 0; t < TT; ++t) {
                const float a = (t & 1) ? aB[s][i][t >> 1].y : aB[s][i][t >> 1].x;
                const float cur = a + b2a[i];     // dot + bias, bias last
                mem = lstep(mem, cur);
                if (mem > 1.0f) p |= (1u << t);
            }
            bits2[s][i] = p;
        }
    }

    // ------- Phase C: output layer — ALL 64 lanes run (uniform flow) -------
    // lanes 0..49 own (oc1=l, oc2=l+50); lanes 50..63 compute clamped
    // duplicates (discarded) so every readlane sits in uniform control flow.
    const int oc1 = l;                            // 0..63, always < 100
    const int oc2 = (l < 50) ? (l + 50) : 99;     // clamp for lanes 50..63
    const int base1 = (oc1 >> 2) * 1024 + (oc1 & 3);
    const int base2 = (oc2 >> 2) * 1024 + (oc2 & 3);

    v2f aC[2][2][8];                              // [sample][oc-slot][tpair]
#pragma unroll
    for (int s = 0; s < 2; ++s)
#pragma unroll
        for (int o = 0; o < 2; ++o)
#pragma unroll
            for (int tp = 0; tp < 8; ++tp) aC[s][o][tp] = (v2f)0.f;

    for (int h4 = 0; h4 < 64; ++h4) {
#pragma unroll
        for (int c = 0; c < 4; ++c) {
            const uint32_t p0 =
                (uint32_t)__builtin_amdgcn_readlane((int)bits2[0][c], h4);
            const uint32_t p1 =
                (uint32_t)__builtin_amdgcn_readlane((int)bits2[1][c], h4);
            if (p0 | p1) {
                const int h = h4 * 4 + c;
                const v2f w = {Wout[base1 + h * 4], Wout[base2 + h * 4]};
#pragma unroll
                for (int tp = 0; tp < 8; ++tp) {
                    const uint64_t mp0 = mask_pair(p0, tp);
                    const uint64_t mp1 = mask_pair(p1, tp);
                    PKFMA_BLO(aC[0][0][tp], mp0, w);   // s0, oc1 uses w.lo
                    PKFMA_BHI(aC[0][1][tp], mp0, w);   // s0, oc2 uses w.hi
                    PKFMA_BLO(aC[1][0][tp], mp1, w);   // s1, oc1
                    PKFMA_BHI(aC[1][1][tp], mp1, w);   // s1, oc2
                }
            }
        }
    }

    const float bo1 = bout[oc1], bo2 = bout[oc2];
    int cnt[2][2] = {{0, 0}, {0, 0}};
#pragma unroll
    for (int s = 0; s < 2; ++s) {
        float memA = 0.f, memB = 0.f;
#pragma unroll
        for (int t = 0; t < TT; ++t) {
            const float aA = (t & 1) ? aC[s][0][t >> 1].y : aC[s][0][t >> 1].x;
            const float aB2 = (t & 1) ? aC[s][1][t >> 1].y : aC[s][1][t >> 1].x;
            memA = lstep(memA, aA + bo1);
            memB = lstep(memB, aB2 + bo2);
            if (memA > 1.0f) ++cnt[s][0];
            if (memB > 1.0f) ++cnt[s][1];
        }
    }
    if (l < 50) {
        out[b0 * 100 + oc1]  = (float)cnt[0][0];
        out[b0 * 100 + oc2]  = (float)cnt[0][1];
        out[b1s * 100 + oc1] = (float)cnt[1][0];
        out[b1s * 100 + oc2] = (float)cnt[1][1];
    }
}

extern "C" void kernel_launch(void* const* d_in, const int* in_sizes, int n_in,
                              void* d_out, int out_size, void* d_ws, size_t ws_size,
                              hipStream_t stream) {
    const float* x    = (const float*)d_in[0];
    const float* W1   = (const float*)d_in[1];
    const float* b1   = (const float*)d_in[2];
    const float* W2   = (const float*)d_in[3];
    const float* b2   = (const float*)d_in[4];
    const float* Wout = (const float*)d_in[5];
    const float* bout = (const float*)d_in[6];
    float* out = (float*)d_out;

    const int B = in_sizes[0] / 3;   // 32768
    snn_fast<<<B / 8, 256, 0, stream>>>(x, W1, b1, W2, b2, Wout, bout, out);
}

// Round 5
// 706.093 us; speedup vs baseline: 1.5948x; 1.5948x over previous
//
#include <hip/hip_runtime.h>
#include <stdint.h>

#define TT 16

typedef float v2f __attribute__((ext_vector_type(2)));

// Locked reference semantics (R7 variant A, verified):
//   cur1 = fmaf(x2,w2, fmaf(x1,w1, x0*w0)) + b1          (f32, fma ascending)
//   mem  = fmaf(0.9f, mem, cur) - reset                  (fused recurrence)
//   dots = single-acc ascending-h masked adds, bias added after dot
// Exact rewrites: masked add == fma(m,w,acc), m in {0.0f,1.0f}; pk-fma is
// componentwise IEEE; spike bits in VGPRs + v_readlane.
// R11: t-packed accumulators, SALU mask pairs (u64 of {0x3F800000|0}),
// weight broadcast via VOP3P op_sel. Bit-exact.
// R13 (this round): Phase C reads Wout from LDS, transposed wlds[h][oc].
//   R1/R3 both pinned at ~1.6M cyc/CU of TA/L1 line traffic; Phase C's
//   strided gathers were 8K of the 12K lines/wave at 25% line utilization.
//   Wout (100KB) is staged in 2 h-passes of 51.2KB (fits static LDS, 2
//   blocks/CU); 512-thread blocks amortize staging over 8 samples. ds_read
//   lane-consecutive -> 2-way bank alias (free). Accumulators aC persist
//   across passes; h order stays ascending -> bit-exact.
// R12/R4 LESSON: 2-sample accumulator doubling demoted acc arrays to
//   scratch (VGPR_Count=76 < live floats!) -> 1126us. Do not grow per-wave
//   accumulator state; R3's Phase A/B codegen is kept VERBATIM.
// R10/R2 LESSON: removing `if(p)` lets the scheduler hoist loads across
//   iterations -> VGPR blowup -> spill churn -> 2.3x slower. The `if(p)`
//   is a live-range fence; keep loads inside it.
// READLANE LEGALITY (R8 bug): llvm.amdgcn.readlane from an inactive lane is
//   undefined. All readlanes (and their defs) sit in uniform control flow.
//   Phase C runs on all 64 lanes; lanes 50..63 compute a clamped duplicate
//   head; only the final store is divergent. Barriers sit in uniform flow.
__device__ __forceinline__ float lstep(float mem, float cur) {
    const float reset = (mem > 1.0f) ? 1.0f : 0.0f;
    return __builtin_fmaf(0.9f, mem, cur) - reset;
}

// {m_t, m_t+1} as two u32 float-bit-patterns in one u64 (lo = t, hi = t+1).
// p is wave-uniform (readlane result) -> pure SALU (s_bfe + s_mul per half).
__device__ __forceinline__ uint64_t mask_pair(uint32_t p, int tp) {
    const uint32_t lo = ((p >> (2 * tp)) & 1u) * 0x3F800000u;
    const uint32_t hi = ((p >> (2 * tp + 1)) & 1u) * 0x3F800000u;
    return ((uint64_t)hi << 32) | (uint64_t)lo;
}

// acc.{lo,hi} += m.{lo,hi} * broadcast(w.lo)   [src1 lo-half to both lanes]
#define PKFMA_BLO(acc, mp, w)                                              \
    asm("v_pk_fma_f32 %0, %1, %2, %0 op_sel:[0,0,0] op_sel_hi:[1,0,1]"     \
        : "+v"(acc) : "s"(mp), "v"(w))
// acc.{lo,hi} += m.{lo,hi} * broadcast(w.hi)   [src1 hi-half to both lanes]
#define PKFMA_BHI(acc, mp, w)                                              \
    asm("v_pk_fma_f32 %0, %1, %2, %0 op_sel:[0,1,0] op_sel_hi:[1,1,1]"     \
        : "+v"(acc) : "s"(mp), "v"(w))

__global__ __launch_bounds__(512, 2) void snn_fast(
    const float* __restrict__ x,     // [B,3]
    const float* __restrict__ W1,    // [3,256]
    const float* __restrict__ b1,    // [256]
    const float* __restrict__ W2,    // [256,256]
    const float* __restrict__ b2,    // [256]
    const float* __restrict__ Wout,  // [25,256,4]
    const float* __restrict__ bout,  // [25,4]
    float* __restrict__ out)         // [B,25,4]
{
#pragma clang fp contract(off)
    const int tid = threadIdx.x;
    const int l   = tid & 63;                 // lane; owns hidden units 4l..4l+3
    const int b   = blockIdx.x * 8 + (tid >> 6);   // 8 samples per block

    // wlds[h_local][oc]: one 128-h half of Wout, transposed. 51.2 KB.
    __shared__ float wlds[128 * 100];

    // ---------------- Phase A: layer 1 (verbatim R3 structure) -------------
    const float x0 = x[b * 3 + 0], x1 = x[b * 3 + 1], x2 = x[b * 3 + 2];
    const float4 w1r0 = ((const float4*)W1)[l];
    const float4 w1r1 = ((const float4*)W1)[64 + l];
    const float4 w1r2 = ((const float4*)W1)[128 + l];
    const float4 b1v  = ((const float4*)b1)[l];

    const float wa0[4] = {w1r0.x, w1r0.y, w1r0.z, w1r0.w};
    const float wa1[4] = {w1r1.x, w1r1.y, w1r1.z, w1r1.w};
    const float wa2[4] = {w1r2.x, w1r2.y, w1r2.z, w1r2.w};
    const float bb1[4] = {b1v.x, b1v.y, b1v.z, b1v.w};

    uint32_t b1r[4];   // spike bits for h = 4l+i, live in VGPRs
#pragma unroll
    for (int i = 0; i < 4; ++i) {
        const float cur = fmaf(x2, wa2[i], fmaf(x1, wa1[i], x0 * wa0[i])) + bb1[i];
        float mem = 0.f; uint32_t p = 0;
#pragma unroll
        for (int t = 0; t < TT; ++t) {
            mem = lstep(mem, cur);
            if (mem > 1.0f) p |= (1u << t);
        }
        b1r[i] = p;
    }

    // ------- Phase B: layer 2 — t-packed accs, SALU masks (verbatim R3) ----
    v2f accB[4][8];
#pragma unroll
    for (int jj = 0; jj < 4; ++jj)
#pragma unroll
        for (int tp = 0; tp < 8; ++tp) accB[jj][tp] = (v2f)0.f;

    const float4* W2v = (const float4*)W2;
    for (int h4 = 0; h4 < 64; ++h4) {
#pragma unroll
        for (int c = 0; c < 4; ++c) {
            const uint32_t p =
                (uint32_t)__builtin_amdgcn_readlane((int)b1r[c], h4);
            if (p) {                              // wave-uniform skip + fence
                const float4 w = W2v[(h4 * 4 + c) * 64 + l];
                const v2f w01 = {w.x, w.y};
                const v2f w23 = {w.z, w.w};
#pragma unroll
                for (int tp = 0; tp < 8; ++tp) {
                    const uint64_t mp = mask_pair(p, tp);
                    PKFMA_BLO(accB[0][tp], mp, w01);
                    PKFMA_BHI(accB[1][tp], mp, w01);
                    PKFMA_BLO(accB[2][tp], mp, w23);
                    PKFMA_BHI(accB[3][tp], mp, w23);
                }
            }
        }
    }

    const float4 b2v = ((const float4*)b2)[l];
    const float b2a[4] = {b2v.x, b2v.y, b2v.z, b2v.w};
    uint32_t b2r[4];
#pragma unroll
    for (int i = 0; i < 4; ++i) {
        float mem = 0.f; uint32_t p = 0;
#pragma unroll
        for (int t = 0; t < TT; ++t) {
            const float a = (t & 1) ? accB[i][t >> 1].y : accB[i][t >> 1].x;
            const float cur = a + b2a[i];         // dot + bias, bias last
            mem = lstep(mem, cur);
            if (mem > 1.0f) p |= (1u << t);
        }
        b2r[i] = p;
    }

    // ------- Phase C: output layer via LDS-staged transposed Wout ----------
    // lanes 0..49 own (oc1=l, oc2=l+50); lanes 50..63 compute clamped
    // duplicates (discarded) so every readlane sits in uniform control flow.
    const int oc1 = l;                            // 0..63, always < 100
    const int oc2 = (l < 50) ? (l + 50) : 99;     // clamp for lanes 50..63

    v2f aC[2][8];                                 // [oc-slot][tpair]
#pragma unroll
    for (int o = 0; o < 2; ++o)
#pragma unroll
        for (int tp = 0; tp < 8; ++tp) aC[o][tp] = (v2f)0.f;

    for (int pass = 0; pass < 2; ++pass) {
        const int h0 = pass * 128;                // global h base of this half
        __syncthreads();                          // prior pass fully consumed
        // Stage: wlds[h-h0][hb*4+c] = Wout[hb][h][c]; src reads contiguous.
        for (int hb = 0; hb < 25; ++hb) {
            wlds[(tid >> 2) * 100 + hb * 4 + (tid & 3)] =
                Wout[hb * 1024 + h0 * 4 + tid];
        }
        __syncthreads();

        for (int h4 = 0; h4 < 32; ++h4) {
#pragma unroll
            for (int c = 0; c < 4; ++c) {
                const uint32_t p = (uint32_t)__builtin_amdgcn_readlane(
                    (int)b2r[c], pass * 32 + h4);
                if (p) {                          // wave-uniform skip + fence
                    const int hl = h4 * 4 + c;    // local h in [0,128)
                    const v2f w = {wlds[hl * 100 + oc1], wlds[hl * 100 + oc2]};
#pragma unroll
                    for (int tp = 0; tp < 8; ++tp) {
                        const uint64_t mp = mask_pair(p, tp);
                        PKFMA_BLO(aC[0][tp], mp, w);   // oc1 uses w.lo
                        PKFMA_BHI(aC[1][tp], mp, w);   // oc2 uses w.hi
                    }
                }
            }
        }
    }

    const float bo1 = bout[oc1], bo2 = bout[oc2];
    float memA = 0.f, memB = 0.f;
    int cntA = 0, cntB = 0;
#pragma unroll
    for (int t = 0; t < TT; ++t) {
        const float aA = (t & 1) ? aC[0][t >> 1].y : aC[0][t >> 1].x;
        const float aB = (t & 1) ? aC[1][t >> 1].y : aC[1][t >> 1].x;
        memA = lstep(memA, aA + bo1);
        memB = lstep(memB, aB + bo2);
        if (memA > 1.0f) ++cntA;
        if (memB > 1.0f) ++cntB;
    }
    if (l < 50) {
        out[b * 100 + oc1] = (float)cntA;
        out[b * 100 + oc2] = (float)cntB;
    }
}

extern "C" void kernel_launch(void* const* d_in, const int* in_sizes, int n_in,
                              void* d_out, int out_size, void* d_ws, size_t ws_size,
                              hipStream_t stream) {
    const float* x    = (const float*)d_in[0];
    const float* W1   = (const float*)d_in[1];
    const float* b1   = (const float*)d_in[2];
    const float* W2   = (const float*)d_in[3];
    const float* b2   = (const float*)d_in[4];
    const float* Wout = (const float*)d_in[5];
    const float* bout = (const float*)d_in[6];
    float* out = (float*)d_out;

    const int B = in_sizes[0] / 3;   // 32768
    snn_fast<<<B / 8, 512, 0, stream>>>(x, W1, b1, W2, b2, Wout, bout, out);
}

// Round 6
// 668.489 us; speedup vs baseline: 1.6845x; 1.0563x over previous
//
#include <hip/hip_runtime.h>
#include <stdint.h>

#define TT 16

typedef float v2f __attribute__((ext_vector_type(2)));

// ===== FINAL (restored R1 = session best, 672 µs measured) =====
// Locked reference semantics (R7 variant A, verified):
//   cur1 = fmaf(x2,w2, fmaf(x1,w1, x0*w0)) + b1          (f32, fma ascending)
//   mem  = fmaf(0.9f, mem, cur) - reset                  (fused recurrence)
//   dots = single-acc ascending-h masked adds, bias added after dot
// Exact rewrites: masked add == fma(m,w,acc), m in {0.0f,1.0f}; pk-fma is
// componentwise IEEE; spike bits in VGPRs + v_readlane.
//
// SESSION FINDINGS (R1-R5), kept here as the journal of why this shape:
// * The kernel is ISSUE-BOUND: per-SIMD issue model (2 cyc/VALU + 1/SALU +
//   1/branch/mem) reproduces all six measured durations within ~±8%.
//   VALU count, TA line traffic, and occupancy each varied 1.5-3x across
//   rounds with NO duration change - none of them is the binding resource.
// * Mask materialization is a conservation law: ~2-3 issue slots per mask
//   word in every formulation (SALU pair-build / v_cvt / cndmask / exec-mask
//   / readlane-broadcast). R1's s_bfe+v_cvt (3 slots, hazard-free) measured
//   BETTER than R3/R5's 2-SALU build (scalar->VALU forwarding hazards).
// * R2 LESSON: removing `if(p)` -> load hoisting -> VGPR blowup -> spill
//   churn -> 2.3x slower. The `if(p)` is a live-range fence; keep it.
// * R4 LESSON: 2-sample accumulator doubling -> true VGPR ~304 > 256 cap
//   (VGPR_Count is granules of 4) -> spills -> 1.6x slower. Shareable
//   overhead is only ~6 slots/(h,c) anyway (~3% EV). Do not retry.
// * R5 LESSON: LDS-staging Wout (Phase C) removed 2/3 of TA lines: neutral.
// READLANE LEGALITY (R8 bug): llvm.amdgcn.readlane from an inactive lane is
// undefined, and the compiler may sink the source computation into a
// divergent branch. Therefore ALL readlanes (and the defs they read) must
// sit in uniform control flow. Phase C runs on all 64 lanes (lanes 50..63
// compute a clamped duplicate head); only the store is divergent.
__device__ __forceinline__ float lstep(float mem, float cur) {
    const float reset = (mem > 1.0f) ? 1.0f : 0.0f;
    return __builtin_fmaf(0.9f, mem, cur) - reset;
}

__device__ __forceinline__ float bitmask_f(uint32_t p, int t) {
    float m;
    // p is wave-uniform (readlane result) -> (p>>t)&1 is an s_bfe;
    // v_cvt_f32_u32 with SGPR src0 materializes 0.0f/1.0f in 1 VALU op.
    asm("v_cvt_f32_u32 %0, %1" : "=v"(m) : "s"((p >> t) & 1u));
    return m;
}

__global__ __launch_bounds__(256, 4) void snn_fast(
    const float* __restrict__ x,     // [B,3]
    const float* __restrict__ W1,    // [3,256]
    const float* __restrict__ b1,    // [256]
    const float* __restrict__ W2,    // [256,256]
    const float* __restrict__ b2,    // [256]
    const float* __restrict__ Wout,  // [25,256,4]
    const float* __restrict__ bout,  // [25,4]
    float* __restrict__ out)         // [B,25,4]
{
#pragma clang fp contract(off)
    const int tid = threadIdx.x;
    const int l   = tid & 63;                 // lane; owns hidden units 4l..4l+3
    const int b   = blockIdx.x * 4 + (tid >> 6);

    // ---------------- Phase A: layer 1 ----------------
    const float x0 = x[b * 3 + 0], x1 = x[b * 3 + 1], x2 = x[b * 3 + 2];
    const float4 w1r0 = ((const float4*)W1)[l];
    const float4 w1r1 = ((const float4*)W1)[64 + l];
    const float4 w1r2 = ((const float4*)W1)[128 + l];
    const float4 b1v  = ((const float4*)b1)[l];

    const float wa0[4] = {w1r0.x, w1r0.y, w1r0.z, w1r0.w};
    const float wa1[4] = {w1r1.x, w1r1.y, w1r1.z, w1r1.w};
    const float wa2[4] = {w1r2.x, w1r2.y, w1r2.z, w1r2.w};
    const float bb1[4] = {b1v.x, b1v.y, b1v.z, b1v.w};

    uint32_t b1r[4];   // spike bits for h = 4l+i, live in VGPRs
#pragma unroll
    for (int i = 0; i < 4; ++i) {
        const float cur = fmaf(x2, wa2[i], fmaf(x1, wa1[i], x0 * wa0[i])) + bb1[i];
        float mem = 0.f; uint32_t p = 0;
#pragma unroll
        for (int t = 0; t < TT; ++t) {
            mem = lstep(mem, cur);
            if (mem > 1.0f) p |= (1u << t);
        }
        b1r[i] = p;
    }

    // ------- Phase B: layer 2, t-batched branchless pk-fma (uniform flow) ----
    v2f acc0[TT], acc1[TT];   // acc0: j=4l,4l+1  acc1: j=4l+2,4l+3
#pragma unroll
    for (int t = 0; t < TT; ++t) { acc0[t] = (v2f)0.f; acc1[t] = (v2f)0.f; }

    const float4* W2v = (const float4*)W2;
    for (int h4 = 0; h4 < 64; ++h4) {
#pragma unroll
        for (int c = 0; c < 4; ++c) {
            const uint32_t p =
                (uint32_t)__builtin_amdgcn_readlane((int)b1r[c], h4);
            if (p) {                              // wave-uniform skip
                const float4 w = W2v[(h4 * 4 + c) * 64 + l];
                const v2f w01 = {w.x, w.y};
                const v2f w23 = {w.z, w.w};
#pragma unroll
                for (int t = 0; t < TT; ++t) {
                    const float m = bitmask_f(p, t);
                    const v2f mm = {m, m};
                    acc0[t] = __builtin_elementwise_fma(mm, w01, acc0[t]);
                    acc1[t] = __builtin_elementwise_fma(mm, w23, acc1[t]);
                }
            }
        }
    }

    const float4 b2v = ((const float4*)b2)[l];
    const float b2a[4] = {b2v.x, b2v.y, b2v.z, b2v.w};
    uint32_t b2r[4];
#pragma unroll
    for (int i = 0; i < 4; ++i) {
        float mem = 0.f; uint32_t p = 0;
#pragma unroll
        for (int t = 0; t < TT; ++t) {
            const float a = (i < 2) ? ((i == 0) ? acc0[t].x : acc0[t].y)
                                    : ((i == 2) ? acc1[t].x : acc1[t].y);
            const float cur = a + b2a[i];         // dot + bias, bias last
            mem = lstep(mem, cur);
            if (mem > 1.0f) p |= (1u << t);
        }
        b2r[i] = p;
    }

    // ------- Phase C: output layer — ALL 64 lanes run (uniform flow) ---------
    // lanes 0..49 own (oc1=l, oc2=l+50); lanes 50..63 compute clamped
    // duplicates (discarded) so every readlane sits in uniform control flow.
    const int oc1 = l;                            // 0..63, always < 100
    const int oc2 = (l < 50) ? (l + 50) : 99;     // clamp for lanes 50..63
    const int base1 = (oc1 >> 2) * 1024 + (oc1 & 3);
    const int base2 = (oc2 >> 2) * 1024 + (oc2 & 3);

    v2f acco[TT];
#pragma unroll
    for (int t = 0; t < TT; ++t) acco[t] = (v2f)0.f;

    for (int h4 = 0; h4 < 64; ++h4) {
#pragma unroll
        for (int c = 0; c < 4; ++c) {
            const uint32_t p =
                (uint32_t)__builtin_amdgcn_readlane((int)b2r[c], h4);
            if (p) {
                const int h = h4 * 4 + c;
                const v2f w = {Wout[base1 + h * 4], Wout[base2 + h * 4]};
#pragma unroll
                for (int t = 0; t < TT; ++t) {
                    const float m = bitmask_f(p, t);
                    const v2f mm = {m, m};
                    acco[t] = __builtin_elementwise_fma(mm, w, acco[t]);
                }
            }
        }
    }

    const float bo1 = bout[oc1], bo2 = bout[oc2];
    float memA = 0.f, memB = 0.f;
    int cntA = 0, cntB = 0;
#pragma unroll
    for (int t = 0; t < TT; ++t) {
        const float curA = acco[t].x + bo1;
        const float curB = acco[t].y + bo2;
        memA = lstep(memA, curA);
        memB = lstep(memB, curB);
        if (memA > 1.0f) ++cntA;
        if (memB > 1.0f) ++cntB;
    }
    if (l < 50) {
        out[b * 100 + oc1] = (float)cntA;
        out[b * 100 + oc2] = (float)cntB;
    }
}

extern "C" void kernel_launch(void* const* d_in, const int* in_sizes, int n_in,
                              void* d_out, int out_size, void* d_ws, size_t ws_size,
                              hipStream_t stream) {
    const float* x    = (const float*)d_in[0];
    const float* W1   = (const float*)d_in[1];
    const float* b1   = (const float*)d_in[2];
    const float* W2   = (const float*)d_in[3];
    const float* b2   = (const float*)d_in[4];
    const float* Wout = (const float*)d_in[5];
    const float* bout = (const float*)d_in[6];
    float* out = (float*)d_out;

    const int B = in_sizes[0] / 3;   // 32768
    snn_fast<<<B / 4, 256, 0, stream>>>(x, W1, b1, W2, b2, Wout, bout, out);
}

// Round 7
// 649.809 us; speedup vs baseline: 1.7329x; 1.0287x over previous
//
#include <hip/hip_runtime.h>
#include <stdint.h>

#define TT 16

typedef float v2f __attribute__((ext_vector_type(2)));

// Locked reference semantics (R7 variant A, verified):
//   cur1 = fmaf(x2,w2, fmaf(x1,w1, x0*w0)) + b1          (f32, fma ascending)
//   mem  = fmaf(0.9f, mem, cur) - reset                  (fused recurrence)
//   dots = single-acc ascending-h masked adds, bias added after dot
// Exact rewrites: masked add == fma(m,w,acc), m in {0.0f,1.0f}; pk-fma is
// componentwise IEEE; spike bits in VGPRs + v_readlane.
//
// SESSION MODEL (R1-R6): per-SIMD single-issue, wave64 VALU = 2 slots,
// SALU/branch/mem = 1 slot. R1 = 52K slots/wave = 694us (measured 668-700).
// R3 (t-packed SALU masks) = intrinsically 46K slots but measured == R1:
// each mask_pair build sat 1-2 instrs before its consuming pk-fma ->
// s->v hazard wait states ate the saving.
// R14 (this round): R3 structure + HOISTED mask builds. All 8 u64 masks
// built (16 SALU) before the pk-fma burst; sched_barrier(0) pins the order
// so LLVM cannot re-interleave (= R3's failure). Dependency distance >=16
// clears the hazard window. Predicted ~46K slots -> ~600-625us.
// * R2 LESSON: removing `if(p)` -> load hoisting -> VGPR blowup -> spills
//   -> 2.3x. The `if(p)` is a live-range fence; keep loads inside it.
// * R4 LESSON: 2-sample accumulator doubling -> scratch demotion -> 1.6x.
//   Do not grow per-wave accumulator state.
// * R5 LESSON: Phase-C TA lines are not binding (LDS staging was neutral).
// READLANE LEGALITY (R8 bug): llvm.amdgcn.readlane from an inactive lane is
// undefined. All readlanes (and their defs) sit in uniform control flow.
// Phase C runs on all 64 lanes (lanes 50..63 compute a clamped duplicate
// head); only the final store is divergent.
__device__ __forceinline__ float lstep(float mem, float cur) {
    const float reset = (mem > 1.0f) ? 1.0f : 0.0f;
    return __builtin_fmaf(0.9f, mem, cur) - reset;
}

// {m_t, m_t+1} as two u32 float-bit-patterns in one u64 (lo = t, hi = t+1).
// p is wave-uniform (readlane result) -> pure SALU (s_bfe + s_mul per half).
__device__ __forceinline__ uint64_t mask_pair(uint32_t p, int tp) {
    const uint32_t lo = ((p >> (2 * tp)) & 1u) * 0x3F800000u;
    const uint32_t hi = ((p >> (2 * tp + 1)) & 1u) * 0x3F800000u;
    return ((uint64_t)hi << 32) | (uint64_t)lo;
}

// acc.{lo,hi} += m.{lo,hi} * broadcast(w.lo)   [src1 lo-half to both lanes]
#define PKFMA_BLO(acc, mp, w)                                              \
    asm("v_pk_fma_f32 %0, %1, %2, %0 op_sel:[0,0,0] op_sel_hi:[1,0,1]"     \
        : "+v"(acc) : "s"(mp), "v"(w))
// acc.{lo,hi} += m.{lo,hi} * broadcast(w.hi)   [src1 hi-half to both lanes]
#define PKFMA_BHI(acc, mp, w)                                              \
    asm("v_pk_fma_f32 %0, %1, %2, %0 op_sel:[0,1,0] op_sel_hi:[1,1,1]"     \
        : "+v"(acc) : "s"(mp), "v"(w))

__global__ __launch_bounds__(256, 4) void snn_fast(
    const float* __restrict__ x,     // [B,3]
    const float* __restrict__ W1,    // [3,256]
    const float* __restrict__ b1,    // [256]
    const float* __restrict__ W2,    // [256,256]
    const float* __restrict__ b2,    // [256]
    const float* __restrict__ Wout,  // [25,256,4]
    const float* __restrict__ bout,  // [25,4]
    float* __restrict__ out)         // [B,25,4]
{
#pragma clang fp contract(off)
    const int tid = threadIdx.x;
    const int l   = tid & 63;                 // lane; owns hidden units 4l..4l+3
    const int b   = blockIdx.x * 4 + (tid >> 6);

    // ---------------- Phase A: layer 1 ----------------
    const float x0 = x[b * 3 + 0], x1 = x[b * 3 + 1], x2 = x[b * 3 + 2];
    const float4 w1r0 = ((const float4*)W1)[l];
    const float4 w1r1 = ((const float4*)W1)[64 + l];
    const float4 w1r2 = ((const float4*)W1)[128 + l];
    const float4 b1v  = ((const float4*)b1)[l];

    const float wa0[4] = {w1r0.x, w1r0.y, w1r0.z, w1r0.w};
    const float wa1[4] = {w1r1.x, w1r1.y, w1r1.z, w1r1.w};
    const float wa2[4] = {w1r2.x, w1r2.y, w1r2.z, w1r2.w};
    const float bb1[4] = {b1v.x, b1v.y, b1v.z, b1v.w};

    uint32_t b1r[4];   // spike bits for h = 4l+i, live in VGPRs
#pragma unroll
    for (int i = 0; i < 4; ++i) {
        const float cur = fmaf(x2, wa2[i], fmaf(x1, wa1[i], x0 * wa0[i])) + bb1[i];
        float mem = 0.f; uint32_t p = 0;
#pragma unroll
        for (int t = 0; t < TT; ++t) {
            mem = lstep(mem, cur);
            if (mem > 1.0f) p |= (1u << t);
        }
        b1r[i] = p;
    }

    // ------- Phase B: layer 2 — t-packed accs, hoisted SALU masks ----------
    // accB[jj][tp] holds {dot_j(2tp), dot_j(2tp+1)} for j = 4l+jj.
    v2f accB[4][8];
#pragma unroll
    for (int jj = 0; jj < 4; ++jj)
#pragma unroll
        for (int tp = 0; tp < 8; ++tp) accB[jj][tp] = (v2f)0.f;

    const float4* W2v = (const float4*)W2;
    for (int h4 = 0; h4 < 64; ++h4) {
#pragma unroll
        for (int c = 0; c < 4; ++c) {
            const uint32_t p =
                (uint32_t)__builtin_amdgcn_readlane((int)b1r[c], h4);
            if (p) {                              // wave-uniform skip + fence
                const float4 w = W2v[(h4 * 4 + c) * 64 + l];
                const v2f w01 = {w.x, w.y};
                const v2f w23 = {w.z, w.w};
                // Build ALL masks first (16 SALU), then burst the fmas.
                const uint64_t mp0 = mask_pair(p, 0);
                const uint64_t mp1 = mask_pair(p, 1);
                const uint64_t mp2 = mask_pair(p, 2);
                const uint64_t mp3 = mask_pair(p, 3);
                const uint64_t mp4 = mask_pair(p, 4);
                const uint64_t mp5 = mask_pair(p, 5);
                const uint64_t mp6 = mask_pair(p, 6);
                const uint64_t mp7 = mask_pair(p, 7);
                __builtin_amdgcn_sched_barrier(0);  // masks stay hoisted
                PKFMA_BLO(accB[0][0], mp0, w01);
                PKFMA_BHI(accB[1][0], mp0, w01);
                PKFMA_BLO(accB[2][0], mp0, w23);
                PKFMA_BHI(accB[3][0], mp0, w23);
                PKFMA_BLO(accB[0][1], mp1, w01);
                PKFMA_BHI(accB[1][1], mp1, w01);
                PKFMA_BLO(accB[2][1], mp1, w23);
                PKFMA_BHI(accB[3][1], mp1, w23);
                PKFMA_BLO(accB[0][2], mp2, w01);
                PKFMA_BHI(accB[1][2], mp2, w01);
                PKFMA_BLO(accB[2][2], mp2, w23);
                PKFMA_BHI(accB[3][2], mp2, w23);
                PKFMA_BLO(accB[0][3], mp3, w01);
                PKFMA_BHI(accB[1][3], mp3, w01);
                PKFMA_BLO(accB[2][3], mp3, w23);
                PKFMA_BHI(accB[3][3], mp3, w23);
                PKFMA_BLO(accB[0][4], mp4, w01);
                PKFMA_BHI(accB[1][4], mp4, w01);
                PKFMA_BLO(accB[2][4], mp4, w23);
                PKFMA_BHI(accB[3][4], mp4, w23);
                PKFMA_BLO(accB[0][5], mp5, w01);
                PKFMA_BHI(accB[1][5], mp5, w01);
                PKFMA_BLO(accB[2][5], mp5, w23);
                PKFMA_BHI(accB[3][5], mp5, w23);
                PKFMA_BLO(accB[0][6], mp6, w01);
                PKFMA_BHI(accB[1][6], mp6, w01);
                PKFMA_BLO(accB[2][6], mp6, w23);
                PKFMA_BHI(accB[3][6], mp6, w23);
                PKFMA_BLO(accB[0][7], mp7, w01);
                PKFMA_BHI(accB[1][7], mp7, w01);
                PKFMA_BLO(accB[2][7], mp7, w23);
                PKFMA_BHI(accB[3][7], mp7, w23);
            }
        }
    }

    const float4 b2v = ((const float4*)b2)[l];
    const float b2a[4] = {b2v.x, b2v.y, b2v.z, b2v.w};
    uint32_t b2r[4];
#pragma unroll
    for (int i = 0; i < 4; ++i) {
        float mem = 0.f; uint32_t p = 0;
#pragma unroll
        for (int t = 0; t < TT; ++t) {
            const float a = (t & 1) ? accB[i][t >> 1].y : accB[i][t >> 1].x;
            const float cur = a + b2a[i];         // dot + bias, bias last
            mem = lstep(mem, cur);
            if (mem > 1.0f) p |= (1u << t);
        }
        b2r[i] = p;
    }

    // ------- Phase C: output layer — ALL 64 lanes run (uniform flow) -------
    // lanes 0..49 own (oc1=l, oc2=l+50); lanes 50..63 compute clamped
    // duplicates (discarded) so every readlane sits in uniform control flow.
    const int oc1 = l;                            // 0..63, always < 100
    const int oc2 = (l < 50) ? (l + 50) : 99;     // clamp for lanes 50..63
    const int base1 = (oc1 >> 2) * 1024 + (oc1 & 3);
    const int base2 = (oc2 >> 2) * 1024 + (oc2 & 3);

    v2f aC[2][8];                                 // [oc-slot][tpair]
#pragma unroll
    for (int o = 0; o < 2; ++o)
#pragma unroll
        for (int tp = 0; tp < 8; ++tp) aC[o][tp] = (v2f)0.f;

    for (int h4 = 0; h4 < 64; ++h4) {
#pragma unroll
        for (int c = 0; c < 4; ++c) {
            const uint32_t p =
                (uint32_t)__builtin_amdgcn_readlane((int)b2r[c], h4);
            if (p) {
                const int h = h4 * 4 + c;
                const v2f w = {Wout[base1 + h * 4], Wout[base2 + h * 4]};
                const uint64_t mp0 = mask_pair(p, 0);
                const uint64_t mp1 = mask_pair(p, 1);
                const uint64_t mp2 = mask_pair(p, 2);
                const uint64_t mp3 = mask_pair(p, 3);
                const uint64_t mp4 = mask_pair(p, 4);
                const uint64_t mp5 = mask_pair(p, 5);
                const uint64_t mp6 = mask_pair(p, 6);
                const uint64_t mp7 = mask_pair(p, 7);
                __builtin_amdgcn_sched_barrier(0);  // masks stay hoisted
                PKFMA_BLO(aC[0][0], mp0, w);      // oc1 uses w.lo
                PKFMA_BHI(aC[1][0], mp0, w);      // oc2 uses w.hi
                PKFMA_BLO(aC[0][1], mp1, w);
                PKFMA_BHI(aC[1][1], mp1, w);
                PKFMA_BLO(aC[0][2], mp2, w);
                PKFMA_BHI(aC[1][2], mp2, w);
                PKFMA_BLO(aC[0][3], mp3, w);
                PKFMA_BHI(aC[1][3], mp3, w);
                PKFMA_BLO(aC[0][4], mp4, w);
                PKFMA_BHI(aC[1][4], mp4, w);
                PKFMA_BLO(aC[0][5], mp5, w);
                PKFMA_BHI(aC[1][5], mp5, w);
                PKFMA_BLO(aC[0][6], mp6, w);
                PKFMA_BHI(aC[1][6], mp6, w);
                PKFMA_BLO(aC[0][7], mp7, w);
                PKFMA_BHI(aC[1][7], mp7, w);
            }
        }
    }

    const float bo1 = bout[oc1], bo2 = bout[oc2];
    float memA = 0.f, memB = 0.f;
    int cntA = 0, cntB = 0;
#pragma unroll
    for (int t = 0; t < TT; ++t) {
        const float aA = (t & 1) ? aC[0][t >> 1].y : aC[0][t >> 1].x;
        const float aB = (t & 1) ? aC[1][t >> 1].y : aC[1][t >> 1].x;
        memA = lstep(memA, aA + bo1);
        memB = lstep(memB, aB + bo2);
        if (memA > 1.0f) ++cntA;
        if (memB > 1.0f) ++cntB;
    }
    if (l < 50) {
        out[b * 100 + oc1] = (float)cntA;
        out[b * 100 + oc2] = (float)cntB;
    }
}

extern "C" void kernel_launch(void* const* d_in, const int* in_sizes, int n_in,
                              void* d_out, int out_size, void* d_ws, size_t ws_size,
                              hipStream_t stream) {
    const float* x    = (const float*)d_in[0];
    const float* W1   = (const float*)d_in[1];
    const float* b1   = (const float*)d_in[2];
    const float* W2   = (const float*)d_in[3];
    const float* b2   = (const float*)d_in[4];
    const float* Wout = (const float*)d_in[5];
    const float* bout = (const float*)d_in[6];
    float* out = (float*)d_out;

    const int B = in_sizes[0] / 3;   // 32768
    snn_fast<<<B / 4, 256, 0, stream>>>(x, W1, b1, W2, b2, Wout, bout, out);
}